// Round 1
// baseline (2750.730 us; speedup 1.0000x reference)
//
#include <hip/hip_runtime.h>

// GRU: B=128, T=2048, H=128.
// Kernel 1 (gru_proj): xz/xr/xh = x @ W^T + b via bf16 MFMA 16x16x32.
//   xz,xr packed as 2x bf16 into d_out words (consumed then overwritten by h),
//   xh as bf16 into d_ws (67MB).
// Kernel 2 (gru_rec): 1 batch/block, 512 thr; U matrices in VGPRs (96 f32/thr),
//   h broadcast via readlane->SGPR scalar-operand FMA. 4 barriers/step.

#define T_LEN 2048
#define H_DIM 128
#define B_DIM 128

typedef __attribute__((ext_vector_type(8))) __bf16 bf16x8;
typedef __attribute__((ext_vector_type(4))) float f32x4;

__device__ __forceinline__ unsigned short f2bf_bits(float f){
  __bf16 b = (__bf16)f;                     // fptrunc, RNE
  return __builtin_bit_cast(unsigned short, b);
}
__device__ __forceinline__ float bf2f(unsigned short s){
  unsigned int u = ((unsigned int)s) << 16;
  return __builtin_bit_cast(float, u);
}
__device__ __forceinline__ float rdlane(float v, int lane){
  return __builtin_bit_cast(float, __builtin_amdgcn_readlane(__builtin_bit_cast(int, v), lane));
}
__device__ __forceinline__ float sigm(float x){
  return 1.0f / (1.0f + exp2f(-1.4426950408889634f * x));
}
__device__ __forceinline__ float tanh_fast(float x){
  float e = exp2f(2.8853900817779268f * x);   // e^(2x); inf-safe: ->1 / ->-1
  return 1.0f - 2.0f / (e + 1.0f);
}

// ---------------- projection GEMM ----------------

__device__ __forceinline__ void stage_mat128(const float* __restrict__ src,
                                             __bf16 (*dst)[136], int tid){
  #pragma unroll
  for (int rep = 0; rep < 8; ++rep){
    int fi = rep * 2048 + tid * 4;
    float4 v = *reinterpret_cast<const float4*>(src + fi);
    int m = fi >> 7;
    int k = fi & 127;
    unsigned long long pk =
        (unsigned long long)f2bf_bits(v.x)
      | ((unsigned long long)f2bf_bits(v.y) << 16)
      | ((unsigned long long)f2bf_bits(v.z) << 32)
      | ((unsigned long long)f2bf_bits(v.w) << 48);
    *reinterpret_cast<unsigned long long*>(&dst[m][k]) = pk;
  }
}

__global__ __launch_bounds__(512, 2) void gru_proj(
    const float* __restrict__ x,
    const float* __restrict__ Wz, const float* __restrict__ Wr, const float* __restrict__ Wh,
    const float* __restrict__ bz, const float* __restrict__ br, const float* __restrict__ bh,
    unsigned int* __restrict__ out_zr, unsigned short* __restrict__ out_h)
{
  __shared__ __bf16 xs[128][136];         // x tile [m][k], +8 pad
  __shared__ __bf16 wsh[3][128][136];     // W_g as [n][k] (== B^T layout), +8 pad

  const int tid = threadIdx.x;
  const long Mbase = (long)blockIdx.x * 128;

  stage_mat128(x + Mbase * H_DIM, xs, tid);
  stage_mat128(Wz, wsh[0], tid);
  stage_mat128(Wr, wsh[1], tid);
  stage_mat128(Wh, wsh[2], tid);
  __syncthreads();

  const int w  = tid >> 6, l = tid & 63;
  const int ml = l & 15;                  // A-row / B-col lane index
  const int kl = (l >> 4) * 8;            // contiguous-8 k slice
  const int n  = w * 16 + ml;             // this wave owns n-range [16w,16w+16)

  // B fragments: 3 gates x 4 k-steps, held in registers (48 VGPRs)
  bf16x8 bfr[3][4];
  #pragma unroll
  for (int g = 0; g < 3; ++g)
    #pragma unroll
    for (int kk = 0; kk < 4; ++kk)
      bfr[g][kk] = *reinterpret_cast<const bf16x8*>(&wsh[g][n][kk * 32 + kl]);

  const float bzv = bz[n], brv = br[n], bhv = bh[n];

  f32x4 acc[8][3];
  #pragma unroll
  for (int mt = 0; mt < 8; ++mt)
    #pragma unroll
    for (int g = 0; g < 3; ++g)
      acc[mt][g] = (f32x4){0.f, 0.f, 0.f, 0.f};

  #pragma unroll
  for (int mt = 0; mt < 8; ++mt){
    #pragma unroll
    for (int kk = 0; kk < 4; ++kk){
      bf16x8 a = *reinterpret_cast<const bf16x8*>(&xs[mt * 16 + ml][kk * 32 + kl]);
      acc[mt][0] = __builtin_amdgcn_mfma_f32_16x16x32_bf16(a, bfr[0][kk], acc[mt][0], 0, 0, 0);
      acc[mt][1] = __builtin_amdgcn_mfma_f32_16x16x32_bf16(a, bfr[1][kk], acc[mt][1], 0, 0, 0);
      acc[mt][2] = __builtin_amdgcn_mfma_f32_16x16x32_bf16(a, bfr[2][kk], acc[mt][2], 0, 0, 0);
    }
  }

  // C layout: col = lane&15 (==n), row = (lane>>4)*4 + reg   [m89-verified]
  #pragma unroll
  for (int mt = 0; mt < 8; ++mt){
    #pragma unroll
    for (int p = 0; p < 4; ++p){
      long row = Mbase + mt * 16 + (l >> 4) * 4 + p;
      float vz = acc[mt][0][p] + bzv;
      float vr = acc[mt][1][p] + brv;
      float vh = acc[mt][2][p] + bhv;
      unsigned int word = (unsigned int)f2bf_bits(vz)
                        | (((unsigned int)f2bf_bits(vr)) << 16);
      out_zr[row * H_DIM + n] = word;
      out_h [row * H_DIM + n] = f2bf_bits(vh);
    }
  }
}

// ---------------- recurrence ----------------

__global__ __launch_bounds__(512, 2) void gru_rec(
    const float* __restrict__ Uz, const float* __restrict__ Ur, const float* __restrict__ Uh,
    const int* __restrict__ lengths,
    const unsigned int* xzr,            // aliases `out` (packed bf16 xz|xr) - no restrict
    const unsigned short* __restrict__ xh,
    float* out)
{
  __shared__ float h_lds[128];
  __shared__ float rh_lds[128];
  __shared__ float spz[4][128];
  __shared__ float spr[4][128];
  __shared__ float sph[4][128];

  const int tid = threadIdx.x;
  const int w = tid >> 6, l = tid & 63;
  const int q = w >> 1;                 // j-chunk [32q, 32q+32), wave-uniform
  const int u = l + 64 * (w & 1);       // owned output unit
  const int b = blockIdx.x;
  const int len = lengths[b];

  // U rows in registers: 96 VGPRs/thread
  float uz[32], ur[32], uh[32];
  {
    const float* puz = Uz + u * H_DIM + q * 32;
    const float* pur = Ur + u * H_DIM + q * 32;
    const float* puh = Uh + u * H_DIM + q * 32;
    #pragma unroll
    for (int r = 0; r < 8; ++r){
      float4 vz = *reinterpret_cast<const float4*>(puz + r * 4);
      float4 vr = *reinterpret_cast<const float4*>(pur + r * 4);
      float4 vh = *reinterpret_cast<const float4*>(puh + r * 4);
      uz[r*4+0]=vz.x; uz[r*4+1]=vz.y; uz[r*4+2]=vz.z; uz[r*4+3]=vz.w;
      ur[r*4+0]=vr.x; ur[r*4+1]=vr.y; ur[r*4+2]=vr.z; ur[r*4+3]=vr.w;
      uh[r*4+0]=vh.x; uh[r*4+1]=vh.y; uh[r*4+2]=vh.z; uh[r*4+3]=vh.w;
    }
  }

  if (tid < 128) h_lds[tid] = 0.f;
  float h_reg = 0.f, z_keep = 0.f;      // live in reducer threads (tid<128)
  __syncthreads();

  const long base = (long)b * T_LEN * H_DIM;
  const int bq = q * 32 + (l & 31);     // broadcast-source slot

  for (int t = 0; t < len; ++t){
    // prefetch this step's input projections (consumed after bar1/bar3)
    unsigned int  zrw = 0u;
    unsigned short xhw = 0u;
    if (tid < 128){
      zrw = xzr[base + (long)t * H_DIM + tid];
      xhw = xh [base + (long)t * H_DIM + tid];
    }

    // phase A: z,r matvecs. h[32q+jj] broadcast via readlane scalar operand.
    float hbc = h_lds[bq];
    float az = 0.f, ar = 0.f;
    #pragma unroll
    for (int jj = 0; jj < 32; ++jj){
      float sh = rdlane(hbc, jj);
      az = fmaf(uz[jj], sh, az);
      ar = fmaf(ur[jj], sh, ar);
    }
    spz[q][u] = az;
    spr[q][u] = ar;
    __syncthreads();                    // bar1

    if (tid < 128){
      float sz = spz[0][tid] + spz[1][tid] + spz[2][tid] + spz[3][tid];
      float sr = spr[0][tid] + spr[1][tid] + spr[2][tid] + spr[3][tid];
      float zg = sigm(bf2f((unsigned short)(zrw & 0xffffu)) + sz);
      float rg = sigm(bf2f((unsigned short)(zrw >> 16)) + sr);
      z_keep = zg;
      rh_lds[tid] = rg * h_reg;
    }
    __syncthreads();                    // bar2

    // phase B: candidate matvec on r*h
    float rbc = rh_lds[bq];
    float ah = 0.f;
    #pragma unroll
    for (int jj = 0; jj < 32; ++jj){
      ah = fmaf(uh[jj], rdlane(rbc, jj), ah);
    }
    sph[q][u] = ah;
    __syncthreads();                    // bar3

    if (tid < 128){
      float s  = sph[0][tid] + sph[1][tid] + sph[2][tid] + sph[3][tid];
      float hc = tanh_fast(bf2f(xhw) + s);
      float hn = h_reg + z_keep * (hc - h_reg);   // (1-z)h + z*hc
      h_reg = hn;
      h_lds[tid] = hn;
      out[base + (long)t * H_DIM + tid] = hn;     // overwrites consumed xz|xr word
    }
    __syncthreads();                    // bar4
  }

  // masked region: exact zeros for t >= len
  for (long i = (long)len * H_DIM + tid * 4; i < (long)T_LEN * H_DIM; i += 512 * 4){
    *reinterpret_cast<float4*>(out + base + i) = make_float4(0.f, 0.f, 0.f, 0.f);
  }
}

extern "C" void kernel_launch(void* const* d_in, const int* in_sizes, int n_in,
                              void* d_out, int out_size, void* d_ws, size_t ws_size,
                              hipStream_t stream){
  const float* x       = (const float*)d_in[0];
  const int*   lengths = (const int*)  d_in[1];
  const float* Wz = (const float*)d_in[2];
  const float* Uz = (const float*)d_in[3];
  const float* bz = (const float*)d_in[4];
  const float* Wr = (const float*)d_in[5];
  const float* Ur = (const float*)d_in[6];
  const float* br = (const float*)d_in[7];
  const float* Wh = (const float*)d_in[8];
  const float* Uh = (const float*)d_in[9];
  const float* bh = (const float*)d_in[10];

  unsigned int*   zr    = (unsigned int*)d_out;   // packed bf16 xz|xr, then h
  unsigned short* xhbuf = (unsigned short*)d_ws;  // bf16 xh, 67.1 MB

  gru_proj<<<dim3(2048), dim3(512), 0, stream>>>(x, Wz, Wr, Wh, bz, br, bh, zr, xhbuf);
  gru_rec <<<dim3(128),  dim3(512), 0, stream>>>(Uz, Ur, Uh, lengths, zr, xhbuf, (float*)d_out);
}

// Round 2
// 1824.371 us; speedup vs baseline: 1.5078x; 1.5078x over previous
//
#include <hip/hip_runtime.h>

// GRU: B=128, T=2048, H=128.
// Kernel 1 (gru_proj): xz/xr/xh = x @ W^T + b via bf16 MFMA 16x16x32.
//   xz,xr packed as 2x bf16 into d_out words (consumed then overwritten by h),
//   xh as bf16 into d_ws (67MB).
// Kernel 2 (gru_rec): 1 batch/block, 512 thr. In-wave K-split: lane l of wave w
//   owns (u=16w+(l&15), q=l>>4); cross-chunk reduce = shfl_xor butterfly.
//   2 raw barriers/step (no vmcnt drain -> 2-step-deep global prefetch lives
//   across barriers, out-store is fire-and-forget). U in VGPRs (96 f32/thr).

#define T_LEN 2048
#define H_DIM 128
#define B_DIM 128

typedef __attribute__((ext_vector_type(8))) __bf16 bf16x8;
typedef __attribute__((ext_vector_type(4))) float f32x4;

// raw barrier: drains LDS ops (cross-wave visibility) but NOT vmcnt,
// so prefetched global loads / pending stores stay in flight. [m201 pattern]
#define BARRIER() asm volatile("s_waitcnt lgkmcnt(0)\n\ts_barrier" ::: "memory")

__device__ __forceinline__ unsigned short f2bf_bits(float f){
  __bf16 b = (__bf16)f;                     // fptrunc, RNE
  return __builtin_bit_cast(unsigned short, b);
}
__device__ __forceinline__ float bf2f(unsigned short s){
  unsigned int u = ((unsigned int)s) << 16;
  return __builtin_bit_cast(float, u);
}
__device__ __forceinline__ float sigm(float x){
  return 1.0f / (1.0f + exp2f(-1.4426950408889634f * x));
}
__device__ __forceinline__ float tanh_fast(float x){
  float e = exp2f(2.8853900817779268f * x);   // e^(2x); inf-safe: ->1 / ->-1
  return 1.0f - 2.0f / (e + 1.0f);
}

// ---------------- projection GEMM ----------------

__device__ __forceinline__ void stage_mat128(const float* __restrict__ src,
                                             __bf16 (*dst)[136], int tid){
  #pragma unroll
  for (int rep = 0; rep < 8; ++rep){
    int fi = rep * 2048 + tid * 4;
    float4 v = *reinterpret_cast<const float4*>(src + fi);
    int m = fi >> 7;
    int k = fi & 127;
    unsigned long long pk =
        (unsigned long long)f2bf_bits(v.x)
      | ((unsigned long long)f2bf_bits(v.y) << 16)
      | ((unsigned long long)f2bf_bits(v.z) << 32)
      | ((unsigned long long)f2bf_bits(v.w) << 48);
    *reinterpret_cast<unsigned long long*>(&dst[m][k]) = pk;
  }
}

__global__ __launch_bounds__(512, 2) void gru_proj(
    const float* __restrict__ x,
    const float* __restrict__ Wz, const float* __restrict__ Wr, const float* __restrict__ Wh,
    const float* __restrict__ bz, const float* __restrict__ br, const float* __restrict__ bh,
    unsigned int* __restrict__ out_zr, unsigned short* __restrict__ out_h)
{
  __shared__ __bf16 xs[128][136];         // x tile [m][k], +8 pad
  __shared__ __bf16 wsh[3][128][136];     // W_g as [n][k] (== B^T layout), +8 pad

  const int tid = threadIdx.x;
  const long Mbase = (long)blockIdx.x * 128;

  stage_mat128(x + Mbase * H_DIM, xs, tid);
  stage_mat128(Wz, wsh[0], tid);
  stage_mat128(Wr, wsh[1], tid);
  stage_mat128(Wh, wsh[2], tid);
  __syncthreads();

  const int w  = tid >> 6, l = tid & 63;
  const int ml = l & 15;                  // A-row / B-col lane index
  const int kl = (l >> 4) * 8;            // contiguous-8 k slice
  const int n  = w * 16 + ml;             // this wave owns n-range [16w,16w+16)

  // B fragments: 3 gates x 4 k-steps, held in registers (48 VGPRs)
  bf16x8 bfr[3][4];
  #pragma unroll
  for (int g = 0; g < 3; ++g)
    #pragma unroll
    for (int kk = 0; kk < 4; ++kk)
      bfr[g][kk] = *reinterpret_cast<const bf16x8*>(&wsh[g][n][kk * 32 + kl]);

  const float bzv = bz[n], brv = br[n], bhv = bh[n];

  f32x4 acc[8][3];
  #pragma unroll
  for (int mt = 0; mt < 8; ++mt)
    #pragma unroll
    for (int g = 0; g < 3; ++g)
      acc[mt][g] = (f32x4){0.f, 0.f, 0.f, 0.f};

  #pragma unroll
  for (int mt = 0; mt < 8; ++mt){
    #pragma unroll
    for (int kk = 0; kk < 4; ++kk){
      bf16x8 a = *reinterpret_cast<const bf16x8*>(&xs[mt * 16 + ml][kk * 32 + kl]);
      acc[mt][0] = __builtin_amdgcn_mfma_f32_16x16x32_bf16(a, bfr[0][kk], acc[mt][0], 0, 0, 0);
      acc[mt][1] = __builtin_amdgcn_mfma_f32_16x16x32_bf16(a, bfr[1][kk], acc[mt][1], 0, 0, 0);
      acc[mt][2] = __builtin_amdgcn_mfma_f32_16x16x32_bf16(a, bfr[2][kk], acc[mt][2], 0, 0, 0);
    }
  }

  // C layout: col = lane&15 (==n), row = (lane>>4)*4 + reg   [m89-verified]
  #pragma unroll
  for (int mt = 0; mt < 8; ++mt){
    #pragma unroll
    for (int p = 0; p < 4; ++p){
      long row = Mbase + mt * 16 + (l >> 4) * 4 + p;
      float vz = acc[mt][0][p] + bzv;
      float vr = acc[mt][1][p] + brv;
      float vh = acc[mt][2][p] + bhv;
      unsigned int word = (unsigned int)f2bf_bits(vz)
                        | (((unsigned int)f2bf_bits(vr)) << 16);
      out_zr[row * H_DIM + n] = word;
      out_h [row * H_DIM + n] = f2bf_bits(vh);
    }
  }
}

// ---------------- recurrence ----------------
// LDS chunk layout: padded stride 36 floats (chunk q at offset 36q) so the 4
// broadcast-group addresses of a ds_read_b128 land on disjoint banks.

__device__ __forceinline__ void gru_step(
    int t, long base, int l, int q, int u,
    const float* uz, const float* ur, const float* uh,
    float* h_pad, float* rh_pad,
    const unsigned int* xzr, const unsigned short* xh, float* out,
    unsigned int& zrw, unsigned short& xhw, float& h_own, float& zg)
{
  // ---- phase A: z,r partial dots over chunk [32q, 32q+32) ----
  float hc[32];
  #pragma unroll
  for (int r = 0; r < 8; ++r){
    float4 v = *reinterpret_cast<const float4*>(&h_pad[q * 36 + r * 4]);
    hc[r*4+0] = v.x; hc[r*4+1] = v.y; hc[r*4+2] = v.z; hc[r*4+3] = v.w;
  }
  float az = 0.f, ar = 0.f;
  #pragma unroll
  for (int j = 0; j < 32; ++j){
    az = fmaf(uz[j], hc[j], az);
    ar = fmaf(ur[j], hc[j], ar);
  }
  // butterfly over q bits (lane bits 4,5): full sums in every lane
  az += __shfl_xor(az, 16); az += __shfl_xor(az, 32);
  ar += __shfl_xor(ar, 16); ar += __shfl_xor(ar, 32);

  if (l < 16){
    zg = sigm(bf2f((unsigned short)(zrw & 0xffffu)) + az);
    float rg = sigm(bf2f((unsigned short)(zrw >> 16)) + ar);
    rh_pad[u + (u >> 5) * 4] = rg * h_own;
    // refill zr prefetch slot (consumed above) for step t+2
    int tt = t + 2 < T_LEN ? t + 2 : T_LEN - 1;
    zrw = xzr[base + (long)tt * H_DIM + u];
  }
  BARRIER();                              // rh visible; vmcnt untouched

  // ---- phase B: candidate partial dot on r*h ----
  float rc[32];
  #pragma unroll
  for (int r = 0; r < 8; ++r){
    float4 v = *reinterpret_cast<const float4*>(&rh_pad[q * 36 + r * 4]);
    rc[r*4+0] = v.x; rc[r*4+1] = v.y; rc[r*4+2] = v.z; rc[r*4+3] = v.w;
  }
  float ah = 0.f;
  #pragma unroll
  for (int j = 0; j < 32; ++j){
    ah = fmaf(uh[j], rc[j], ah);
  }
  ah += __shfl_xor(ah, 16); ah += __shfl_xor(ah, 32);

  if (l < 16){
    float hcand = tanh_fast(bf2f(xhw) + ah);
    h_own = h_own + zg * (hcand - h_own);   // (1-z)h + z*hc
    h_pad[u + (u >> 5) * 4] = h_own;
    out[base + (long)t * H_DIM + u] = h_own;
    // refill xh prefetch slot for step t+2
    int tt = t + 2 < T_LEN ? t + 2 : T_LEN - 1;
    xhw = xh[base + (long)tt * H_DIM + u];
  }
  BARRIER();                              // h' visible; vmcnt untouched
}

__global__ __launch_bounds__(512, 2) void gru_rec(
    const float* __restrict__ Uz, const float* __restrict__ Ur, const float* __restrict__ Uh,
    const int* __restrict__ lengths,
    const unsigned int* xzr,            // aliases `out` (packed bf16 xz|xr) - no restrict
    const unsigned short* __restrict__ xh,
    float* out)
{
  __shared__ __align__(16) float h_pad[144];
  __shared__ __align__(16) float rh_pad[144];

  const int tid = threadIdx.x;
  const int w = tid >> 6, l = tid & 63;
  const int q = l >> 4;                 // K-chunk [32q, 32q+32), in-wave
  const int u = w * 16 + (l & 15);      // owned output unit
  const int b = blockIdx.x;
  const int len = lengths[b];

  // U rows for (u, chunk q) in registers: 96 VGPRs/thread
  float uz[32], ur[32], uh[32];
  {
    const float* puz = Uz + u * H_DIM + q * 32;
    const float* pur = Ur + u * H_DIM + q * 32;
    const float* puh = Uh + u * H_DIM + q * 32;
    #pragma unroll
    for (int r = 0; r < 8; ++r){
      float4 vz = *reinterpret_cast<const float4*>(puz + r * 4);
      float4 vr = *reinterpret_cast<const float4*>(pur + r * 4);
      float4 vh = *reinterpret_cast<const float4*>(puh + r * 4);
      uz[r*4+0]=vz.x; uz[r*4+1]=vz.y; uz[r*4+2]=vz.z; uz[r*4+3]=vz.w;
      ur[r*4+0]=vr.x; ur[r*4+1]=vr.y; ur[r*4+2]=vr.z; ur[r*4+3]=vr.w;
      uh[r*4+0]=vh.x; uh[r*4+1]=vh.y; uh[r*4+2]=vh.z; uh[r*4+3]=vh.w;
    }
  }

  if (tid < 144) h_pad[tid] = 0.f;
  float h_own = 0.f, zg = 0.f;          // live in l<16 lanes
  __syncthreads();

  const long base = (long)b * T_LEN * H_DIM;

  // 2-deep prefetch pipeline: named regs (no runtime-indexed arrays)
  unsigned int  zrwA = 0u, zrwB = 0u;
  unsigned short xhwA = 0u, xhwB = 0u;
  if (l < 16){
    zrwA = xzr[base + 0 * H_DIM + u];
    xhwA = xh [base + 0 * H_DIM + u];
    zrwB = xzr[base + 1 * H_DIM + u];   // buffer valid through T_LEN-1
    xhwB = xh [base + 1 * H_DIM + u];
  }

  int t = 0;
  for (; t + 1 < len; t += 2){
    gru_step(t,     base, l, q, u, uz, ur, uh, h_pad, rh_pad, xzr, xh, out, zrwA, xhwA, h_own, zg);
    gru_step(t + 1, base, l, q, u, uz, ur, uh, h_pad, rh_pad, xzr, xh, out, zrwB, xhwB, h_own, zg);
  }
  if (t < len){
    gru_step(t,     base, l, q, u, uz, ur, uh, h_pad, rh_pad, xzr, xh, out, zrwA, xhwA, h_own, zg);
  }

  // masked region: exact zeros for t >= len
  for (long i = (long)len * H_DIM + tid * 4; i < (long)T_LEN * H_DIM; i += 512 * 4){
    *reinterpret_cast<float4*>(out + base + i) = make_float4(0.f, 0.f, 0.f, 0.f);
  }
}

extern "C" void kernel_launch(void* const* d_in, const int* in_sizes, int n_in,
                              void* d_out, int out_size, void* d_ws, size_t ws_size,
                              hipStream_t stream){
  const float* x       = (const float*)d_in[0];
  const int*   lengths = (const int*)  d_in[1];
  const float* Wz = (const float*)d_in[2];
  const float* Uz = (const float*)d_in[3];
  const float* bz = (const float*)d_in[4];
  const float* Wr = (const float*)d_in[5];
  const float* Ur = (const float*)d_in[6];
  const float* br = (const float*)d_in[7];
  const float* Wh = (const float*)d_in[8];
  const float* Uh = (const float*)d_in[9];
  const float* bh = (const float*)d_in[10];

  unsigned int*   zr    = (unsigned int*)d_out;   // packed bf16 xz|xr, then h
  unsigned short* xhbuf = (unsigned short*)d_ws;  // bf16 xh, 67.1 MB

  gru_proj<<<dim3(2048), dim3(512), 0, stream>>>(x, Wz, Wr, Wh, bz, br, bh, zr, xhbuf);
  gru_rec <<<dim3(128),  dim3(512), 0, stream>>>(Uz, Ur, Uh, lengths, zr, xhbuf, (float*)d_out);
}